// Round 10
// baseline (261.198 us; speedup 1.0000x reference)
//
#include <hip/hip_runtime.h>
#include <cstdint>
#include <cstddef>

typedef __attribute__((ext_vector_type(8))) short short8;
typedef __attribute__((ext_vector_type(4))) float f32x4;

#define NB 512
#define DD 4096
#define NP 12288   // fused N' = 3*DD  (q | k | v)

// hardware packed f32x2 -> bf16x2 (RNE), 1 VALU op
__device__ __forceinline__ unsigned pk2(float a, float b) {
    unsigned r;
    asm("v_cvt_pk_bf16_f32 %0, %1, %2" : "=v"(r) : "v"(a), "v"(b));
    return r;
}

__device__ __forceinline__ void gload_lds16(const void* g, void* l) {
    __builtin_amdgcn_global_load_lds((const __attribute__((address_space(1))) void*)g,
                                     (__attribute__((address_space(3))) void*)l, 16, 0, 0);
}

// ---------------- x -> bf16 ----------------
__global__ __launch_bounds__(256) void cvt_bf16_kernel(const float* __restrict__ src,
                                                       unsigned short* __restrict__ dst,
                                                       int n8) {
    int i = blockIdx.x * 256 + threadIdx.x;
    if (i >= n8) return;
    const float4* s = (const float4*)src + (size_t)i * 2;
    float4 a = s[0], b = s[1];
    uint4 r;
    r.x = pk2(a.x, a.y);
    r.y = pk2(a.z, a.w);
    r.z = pk2(b.x, b.y);
    r.w = pk2(b.z, b.w);
    ((uint4*)dst)[i] = r;
}

// ---------------- fused qkv GEMM: small-quantum geometry for occupancy ----------------
// WG = 128 thr (2 waves), tile 64M x 64N, wave tile 64M x 32N. Grid 3072 WGs (KS=2)
// -> ~10 blocks/CU (LDS-capped) = 20 waves/CU, vs 12 before. Body identical to R8:
// W direct global->reg (f32 -> cvt_pk bf16 fragments), As 4-buffer via global_load_lds,
// robust order-independent pipeline: 6 vmem ops per body, end-of-body vmcnt(6).
template<int KS>
__global__ __launch_bounds__(128, 5) void gemm_qkv_kernel(
    const unsigned short* __restrict__ xb,
    const float* __restrict__ w0, const float* __restrict__ w1, const float* __restrict__ w2,
    float* __restrict__ part)
{
    constexpr int KLEN = DD / KS;
    constexpr int NIT = KLEN / 32;
    constexpr int NWG = 192 * 8 * KS;
    constexpr int CPX = NWG / 8;

    // XCD-aware bijective swizzle: the 8*KS blocks sharing one 64-row W panel
    // (all mt, kz for one nt) get consecutive orig ids -> same XCD L2.
    const int bid = blockIdx.x;
    const int orig = (bid & 7) * CPX + (bid >> 3);
    const int nt = orig / (8 * KS);          // 0..191  (64-col N' tile)
    const int rest = orig - nt * (8 * KS);
    const int mt = rest / KS;                // 0..7    (64-row M tile)
    const int kz = rest - mt * KS;

    const float* W = (nt < 64) ? w0 : ((nt < 128) ? w1 : w2);
    const int ntl = nt & 63;
    const unsigned short* Abase = xb + (size_t)(mt * 64) * DD + kz * KLEN;
    float* C = part + (size_t)kz * NB * NP;

    __shared__ unsigned short As[4][64 * 32];   // 16 KB

    const int t = threadIdx.x;      // 0..127
    const int l = t & 63;
    const int wv = t >> 6;          // wave = 32-col strip of the 64N tile

    f32x4 acc[4][2];
    #pragma unroll
    for (int i = 0; i < 4; ++i)
        #pragma unroll
        for (int j = 0; j < 2; ++j)
            acc[i][j] = (f32x4){0.f, 0.f, 0.f, 0.f};

    // A staging: 64x32 bf16 tile = 4 KB; 128 thr x 16 B x 2 rounds.
    // round i: row = i*32 + (t>>2), source col chunk pre-swizzled (c ^= (row>>1)&3).
    const int arow0 = (t >> 2);
    const int acol  = (((t & 3) ^ ((t >> 3) & 3)) * 8);
    // fragment read chunk xor (lane-const)
    const int cx = ((l >> 4) ^ ((l >> 1) & 3));

    // W direct-from-global fragment source: lane l covers W row (ntl*64 + wv*32 + fj*16 + (l&15)),
    // k = kt*32 + (l>>4)*8 .. +8 (two float4 halves).
    const float* wsrc = W + (size_t)(ntl * 64 + wv * 32 + (l & 15)) * DD + kz * KLEN + (l >> 4) * 8;

    float4 bank0[2][2], bank1[2][2];   // [fj][half]

    #define LOADB(bk, kt) { _Pragma("unroll") for (int fj = 0; fj < 2; ++fj) \
                              _Pragma("unroll") for (int h = 0; h < 2; ++h) \
                                bk[fj][h] = *(const float4*)(wsrc + (size_t)(fj * 16) * DD + (kt) * 32 + h * 4); }
    #define STAGEA(kt, buf) { _Pragma("unroll") for (int i = 0; i < 2; ++i) \
                               gload_lds16(Abase + (size_t)(i * 32 + arow0) * DD + (kt) * 32 + acol, \
                                           (char*)(&As[buf][0]) + i * 2048 + wv * 1024); }

    #define BODY(kt, BK, PF_OK, VMC) { \
        short8 bfr[2]; \
        _Pragma("unroll") for (int fj = 0; fj < 2; ++fj) { \
            union { uint4 u; short8 s; } cv; \
            cv.u.x = pk2(BK[fj][0].x, BK[fj][0].y); \
            cv.u.y = pk2(BK[fj][0].z, BK[fj][0].w); \
            cv.u.z = pk2(BK[fj][1].x, BK[fj][1].y); \
            cv.u.w = pk2(BK[fj][1].z, BK[fj][1].w); \
            bfr[fj] = cv.s; \
        } \
        if (PF_OK) { STAGEA((kt) + 2, ((kt) + 2) & 3); LOADB(BK, (kt) + 2); } \
        __builtin_amdgcn_s_setprio(1); \
        _Pragma("unroll") for (int fi = 0; fi < 4; ++fi) { \
            int row = fi * 16 + (l & 15); \
            short8 af = *(const short8*)((const char*)(&As[(kt) & 3][0]) + row * 64 + cx * 16); \
            acc[fi][0] = __builtin_amdgcn_mfma_f32_16x16x32_bf16(af, bfr[0], acc[fi][0], 0, 0, 0); \
            acc[fi][1] = __builtin_amdgcn_mfma_f32_16x16x32_bf16(af, bfr[1], acc[fi][1], 0, 0, 0); \
        } \
        __builtin_amdgcn_s_setprio(0); \
        asm volatile("s_waitcnt vmcnt(" #VMC ") lgkmcnt(0)" ::: "memory"); \
        __builtin_amdgcn_sched_barrier(0); \
        __builtin_amdgcn_s_barrier(); \
        __builtin_amdgcn_sched_barrier(0); \
    }

    // prologue: A0,A1 staged; W0,W1 -> banks; full drain.
    STAGEA(0, 0);
    STAGEA(1, 1);
    LOADB(bank0, 0);
    LOADB(bank1, 1);
    asm volatile("s_waitcnt vmcnt(0) lgkmcnt(0)" ::: "memory");
    __builtin_amdgcn_s_barrier();
    __builtin_amdgcn_sched_barrier(0);

    // main: each body leaves its own 6 vmem ops in flight (vmcnt(6)),
    // draining the previous body's 6 regardless of intra-body issue order.
    for (int kt = 0; kt + 2 < NIT; kt += 2) {
        BODY(kt,     bank0, true, 6);
        BODY(kt + 1, bank1, true, 6);
    }
    // tail (NIT even): full drains, no prefetch.
    BODY(NIT - 2, bank0, false, 0);
    BODY(NIT - 1, bank1, false, 0);

    #undef BODY
    #undef LOADB
    #undef STAGEA

    #pragma unroll
    for (int fi = 0; fi < 4; ++fi) {
        int rbase = mt * 64 + fi * 16 + (l >> 4) * 4;
        #pragma unroll
        for (int fj = 0; fj < 2; ++fj) {
            int col = nt * 64 + wv * 32 + fj * 16 + (l & 15);
            #pragma unroll
            for (int r = 0; r < 4; ++r)
                C[(size_t)(rbase + r) * NP + col] = acc[fi][fj][r];
        }
    }
}

// ---------------- per-batch attention (f32 VALU) + split-K reduce ----------------
template<int KS>
__global__ __launch_bounds__(256) void attn_kernel(
    const float* __restrict__ part,
    const float* __restrict__ x,
    const float* __restrict__ imap,
    float* __restrict__ dout)
{
    const int b = blockIdx.x;
    const int t = threadIdx.x;
    const int l = t & 63;
    const int wv = t >> 6;

    __shared__ float sq[64 * 68];
    __shared__ float sk[64 * 68];   // reused as P with stride 65
    __shared__ float sv[64 * 68];

    const float* base0 = part + (size_t)b * NP;
    const float* base1 = part + (size_t)NB * NP + (size_t)b * NP;

    #pragma unroll
    for (int i = 0; i < 4; ++i) {
        int f4 = i * 256 + t;
        int r = f4 >> 4, c = (f4 & 15) * 4;
        float4 q4 = *(const float4*)(base0 + (size_t)f4 * 4);
        float4 k4 = *(const float4*)(base0 + DD + (size_t)f4 * 4);
        float4 v4 = *(const float4*)(base0 + 2 * DD + (size_t)f4 * 4);
        if (KS == 2) {
            float4 a4 = *(const float4*)(base1 + (size_t)f4 * 4);
            float4 b4 = *(const float4*)(base1 + DD + (size_t)f4 * 4);
            float4 c4 = *(const float4*)(base1 + 2 * DD + (size_t)f4 * 4);
            q4.x += a4.x; q4.y += a4.y; q4.z += a4.z; q4.w += a4.w;
            k4.x += b4.x; k4.y += b4.y; k4.z += b4.z; k4.w += b4.w;
            v4.x += c4.x; v4.y += c4.y; v4.z += c4.z; v4.w += c4.w;
        }
        *(float4*)(&sq[r * 68 + c]) = q4;
        *(float4*)(&sk[r * 68 + c]) = k4;
        *(float4*)(&sv[r * 68 + c]) = v4;
    }
    __syncthreads();

    float accs[16];
    #pragma unroll
    for (int i = 0; i < 16; ++i) accs[i] = 0.f;
    #pragma unroll 4
    for (int f4 = 0; f4 < 16; ++f4) {
        float4 kvv = *(const float4*)(&sk[l * 68 + f4 * 4]);
        #pragma unroll
        for (int i = 0; i < 16; ++i) {
            int h = i * 4 + wv;
            float4 qv = *(const float4*)(&sq[h * 68 + f4 * 4]);
            accs[i] = fmaf(qv.x, kvv.x, fmaf(qv.y, kvv.y, fmaf(qv.z, kvv.z, fmaf(qv.w, kvv.w, accs[i]))));
        }
    }
    __syncthreads();
    #pragma unroll
    for (int i = 0; i < 16; ++i) {
        int h = i * 4 + wv;
        float m = imap[(size_t)b * DD + h * 64 + l];
        sk[h * 65 + l] = accs[i] * 0.125f * m;
    }
    __syncthreads();

    {
        int h = t >> 2, j = t & 3;
        float e[16];
        float mx = -3.0e38f;
        #pragma unroll
        for (int q2 = 0; q2 < 16; ++q2) {
            e[q2] = sk[h * 65 + j * 16 + q2];
            mx = fmaxf(mx, e[q2]);
        }
        mx = fmaxf(mx, __shfl_xor(mx, 1));
        mx = fmaxf(mx, __shfl_xor(mx, 2));
        float s = 0.f;
        #pragma unroll
        for (int q2 = 0; q2 < 16; ++q2) { e[q2] = __expf(e[q2] - mx); s += e[q2]; }
        s += __shfl_xor(s, 1);
        s += __shfl_xor(s, 2);
        float invs = 1.0f / s;
        float* aw = dout + (size_t)NB * DD + (size_t)b * DD + h * 64 + j * 16;
        #pragma unroll
        for (int q2 = 0; q2 < 16; q2 += 4) {
            float4 w4 = {e[q2] * invs, e[q2 + 1] * invs, e[q2 + 2] * invs, e[q2 + 3] * invs};
            *(float4*)(aw + q2) = w4;
            sk[h * 65 + j * 16 + q2 + 0] = w4.x;
            sk[h * 65 + j * 16 + q2 + 1] = w4.y;
            sk[h * 65 + j * 16 + q2 + 2] = w4.z;
            sk[h * 65 + j * 16 + q2 + 3] = w4.w;
        }
    }
    __syncthreads();

    float pacc[16];
    #pragma unroll
    for (int i = 0; i < 16; ++i) pacc[i] = 0.f;
    #pragma unroll 4
    for (int g = 0; g < 64; ++g) {
        float p = sk[l * 65 + g];
        const float4* vr = (const float4*)(&sv[g * 68 + wv * 16]);
        float4 v0 = vr[0], v1 = vr[1], v2 = vr[2], v3 = vr[3];
        pacc[0]  = fmaf(p, v0.x, pacc[0]);
        pacc[1]  = fmaf(p, v0.y, pacc[1]);
        pacc[2]  = fmaf(p, v0.z, pacc[2]);
        pacc[3]  = fmaf(p, v0.w, pacc[3]);
        pacc[4]  = fmaf(p, v1.x, pacc[4]);
        pacc[5]  = fmaf(p, v1.y, pacc[5]);
        pacc[6]  = fmaf(p, v1.z, pacc[6]);
        pacc[7]  = fmaf(p, v1.w, pacc[7]);
        pacc[8]  = fmaf(p, v2.x, pacc[8]);
        pacc[9]  = fmaf(p, v2.y, pacc[9]);
        pacc[10] = fmaf(p, v2.z, pacc[10]);
        pacc[11] = fmaf(p, v2.w, pacc[11]);
        pacc[12] = fmaf(p, v3.x, pacc[12]);
        pacc[13] = fmaf(p, v3.y, pacc[13]);
        pacc[14] = fmaf(p, v3.z, pacc[14]);
        pacc[15] = fmaf(p, v3.w, pacc[15]);
    }
    const size_t ob = (size_t)b * DD + (size_t)(wv * 16) * 64 + l;
    #pragma unroll
    for (int ii = 0; ii < 16; ++ii) {
        size_t o = ob + (size_t)ii * 64;
        dout[o] = x[o] * pacc[ii];
    }
}

extern "C" void kernel_launch(void* const* d_in, const int* in_sizes, int n_in,
                              void* d_out, int out_size, void* d_ws, size_t ws_size,
                              hipStream_t stream) {
    const float* x  = (const float*)d_in[0];
    const float* im = (const float*)d_in[1];
    const float* Wq = (const float*)d_in[2];
    const float* Wk = (const float*)d_in[3];
    const float* Wv = (const float*)d_in[4];
    float* out = (float*)d_out;

    unsigned short* xb = (unsigned short*)d_ws;                        // 4 MiB
    float* part = (float*)((char*)d_ws + (size_t)NB * DD * 2);         // KS * 24 MiB

    const size_t need2 = (size_t)NB * DD * 2 + 2ull * NB * NP * 4;
    const int KS = (ws_size >= need2) ? 2 : 1;

    cvt_bf16_kernel<<<dim3((NB * DD / 8 + 255) / 256), dim3(256), 0, stream>>>(x, xb, NB * DD / 8);

    if (KS == 2) {
        gemm_qkv_kernel<2><<<dim3(192 * 8 * 2), dim3(128), 0, stream>>>(xb, Wq, Wk, Wv, part);
        attn_kernel<2><<<dim3(NB), dim3(256), 0, stream>>>(part, x, im, out);
    } else {
        gemm_qkv_kernel<1><<<dim3(192 * 8 * 1), dim3(128), 0, stream>>>(xb, Wq, Wk, Wv, part);
        attn_kernel<1><<<dim3(NB), dim3(256), 0, stream>>>(part, x, im, out);
    }
}

// Round 11
// 260.243 us; speedup vs baseline: 1.0037x; 1.0037x over previous
//
#include <hip/hip_runtime.h>
#include <cstdint>
#include <cstddef>

typedef __attribute__((ext_vector_type(8))) short short8;
typedef __attribute__((ext_vector_type(4))) float f32x4;

#define NB 512
#define DD 4096
#define NP 12288   // fused N' = 3*DD  (q | k | v)

// hardware packed f32x2 -> bf16x2 (RNE), 1 VALU op
__device__ __forceinline__ unsigned pk2(float a, float b) {
    unsigned r;
    asm("v_cvt_pk_bf16_f32 %0, %1, %2" : "=v"(r) : "v"(a), "v"(b));
    return r;
}

__device__ __forceinline__ void gload_lds16(const void* g, void* l) {
    __builtin_amdgcn_global_load_lds((const __attribute__((address_space(1))) void*)g,
                                     (__attribute__((address_space(3))) void*)l, 16, 0, 0);
}

// ---------------- x -> bf16 ----------------
__global__ __launch_bounds__(256) void cvt_bf16_kernel(const float* __restrict__ src,
                                                       unsigned short* __restrict__ dst,
                                                       int n8) {
    int i = blockIdx.x * 256 + threadIdx.x;
    if (i >= n8) return;
    const float4* s = (const float4*)src + (size_t)i * 2;
    float4 a = s[0], b = s[1];
    uint4 r;
    r.x = pk2(a.x, a.y);
    r.y = pk2(a.z, a.w);
    r.z = pk2(b.x, b.y);
    r.w = pk2(b.z, b.w);
    ((uint4*)dst)[i] = r;
}

// ---------------- fused qkv GEMM: small-quantum geometry for occupancy ----------------
// WG = 128 thr (2 waves), tile 64M x 64N, wave tile 64M x 32N. Grid 3072 WGs (KS=2)
// -> ~10 blocks/CU (LDS-capped) = 20 waves/CU, vs 12 before. Body identical to R8:
// W direct global->reg (f32 -> cvt_pk bf16 fragments), As 4-buffer via global_load_lds,
// robust order-independent pipeline: 6 vmem ops per body, end-of-body vmcnt(6).
template<int KS>
__global__ __launch_bounds__(128, 5) void gemm_qkv_kernel(
    const unsigned short* __restrict__ xb,
    const float* __restrict__ w0, const float* __restrict__ w1, const float* __restrict__ w2,
    float* __restrict__ part)
{
    constexpr int KLEN = DD / KS;
    constexpr int NIT = KLEN / 32;
    constexpr int NWG = 192 * 8 * KS;
    constexpr int CPX = NWG / 8;

    // XCD-aware bijective swizzle: the 8*KS blocks sharing one 64-row W panel
    // (all mt, kz for one nt) get consecutive orig ids -> same XCD L2.
    const int bid = blockIdx.x;
    const int orig = (bid & 7) * CPX + (bid >> 3);
    const int nt = orig / (8 * KS);          // 0..191  (64-col N' tile)
    const int rest = orig - nt * (8 * KS);
    const int mt = rest / KS;                // 0..7    (64-row M tile)
    const int kz = rest - mt * KS;

    const float* W = (nt < 64) ? w0 : ((nt < 128) ? w1 : w2);
    const int ntl = nt & 63;
    const unsigned short* Abase = xb + (size_t)(mt * 64) * DD + kz * KLEN;
    float* C = part + (size_t)kz * NB * NP;

    __shared__ unsigned short As[4][64 * 32];   // 16 KB

    const int t = threadIdx.x;      // 0..127
    const int l = t & 63;
    const int wv = t >> 6;          // wave = 32-col strip of the 64N tile

    f32x4 acc[4][2];
    #pragma unroll
    for (int i = 0; i < 4; ++i)
        #pragma unroll
        for (int j = 0; j < 2; ++j)
            acc[i][j] = (f32x4){0.f, 0.f, 0.f, 0.f};

    // A staging: 64x32 bf16 tile = 4 KB; 128 thr x 16 B x 2 rounds.
    // round i: row = i*32 + (t>>2), source col chunk pre-swizzled (c ^= (row>>1)&3).
    const int arow0 = (t >> 2);
    const int acol  = (((t & 3) ^ ((t >> 3) & 3)) * 8);
    // fragment read chunk xor (lane-const)
    const int cx = ((l >> 4) ^ ((l >> 1) & 3));

    // W direct-from-global fragment source: lane l covers W row (ntl*64 + wv*32 + fj*16 + (l&15)),
    // k = kt*32 + (l>>4)*8 .. +8 (two float4 halves).
    const float* wsrc = W + (size_t)(ntl * 64 + wv * 32 + (l & 15)) * DD + kz * KLEN + (l >> 4) * 8;

    float4 bank0[2][2], bank1[2][2];   // [fj][half]

    #define LOADB(bk, kt) { _Pragma("unroll") for (int fj = 0; fj < 2; ++fj) \
                              _Pragma("unroll") for (int h = 0; h < 2; ++h) \
                                bk[fj][h] = *(const float4*)(wsrc + (size_t)(fj * 16) * DD + (kt) * 32 + h * 4); }
    #define STAGEA(kt, buf) { _Pragma("unroll") for (int i = 0; i < 2; ++i) \
                               gload_lds16(Abase + (size_t)(i * 32 + arow0) * DD + (kt) * 32 + acol, \
                                           (char*)(&As[buf][0]) + i * 2048 + wv * 1024); }

    #define BODY(kt, BK, PF_OK, VMC) { \
        short8 bfr[2]; \
        _Pragma("unroll") for (int fj = 0; fj < 2; ++fj) { \
            union { uint4 u; short8 s; } cv; \
            cv.u.x = pk2(BK[fj][0].x, BK[fj][0].y); \
            cv.u.y = pk2(BK[fj][0].z, BK[fj][0].w); \
            cv.u.z = pk2(BK[fj][1].x, BK[fj][1].y); \
            cv.u.w = pk2(BK[fj][1].z, BK[fj][1].w); \
            bfr[fj] = cv.s; \
        } \
        if (PF_OK) { STAGEA((kt) + 2, ((kt) + 2) & 3); LOADB(BK, (kt) + 2); } \
        __builtin_amdgcn_s_setprio(1); \
        _Pragma("unroll") for (int fi = 0; fi < 4; ++fi) { \
            int row = fi * 16 + (l & 15); \
            short8 af = *(const short8*)((const char*)(&As[(kt) & 3][0]) + row * 64 + cx * 16); \
            acc[fi][0] = __builtin_amdgcn_mfma_f32_16x16x32_bf16(af, bfr[0], acc[fi][0], 0, 0, 0); \
            acc[fi][1] = __builtin_amdgcn_mfma_f32_16x16x32_bf16(af, bfr[1], acc[fi][1], 0, 0, 0); \
        } \
        __builtin_amdgcn_s_setprio(0); \
        asm volatile("s_waitcnt vmcnt(" #VMC ") lgkmcnt(0)" ::: "memory"); \
        __builtin_amdgcn_sched_barrier(0); \
        __builtin_amdgcn_s_barrier(); \
        __builtin_amdgcn_sched_barrier(0); \
    }

    // prologue: A0,A1 staged; W0,W1 -> banks; full drain.
    STAGEA(0, 0);
    STAGEA(1, 1);
    LOADB(bank0, 0);
    LOADB(bank1, 1);
    asm volatile("s_waitcnt vmcnt(0) lgkmcnt(0)" ::: "memory");
    __builtin_amdgcn_s_barrier();
    __builtin_amdgcn_sched_barrier(0);

    // main: each body leaves its own 6 vmem ops in flight (vmcnt(6)),
    // draining the previous body's 6 regardless of intra-body issue order.
    for (int kt = 0; kt + 2 < NIT; kt += 2) {
        BODY(kt,     bank0, true, 6);
        BODY(kt + 1, bank1, true, 6);
    }
    // tail (NIT even): full drains, no prefetch.
    BODY(NIT - 2, bank0, false, 0);
    BODY(NIT - 1, bank1, false, 0);

    #undef BODY
    #undef LOADB
    #undef STAGEA

    #pragma unroll
    for (int fi = 0; fi < 4; ++fi) {
        int rbase = mt * 64 + fi * 16 + (l >> 4) * 4;
        #pragma unroll
        for (int fj = 0; fj < 2; ++fj) {
            int col = nt * 64 + wv * 32 + fj * 16 + (l & 15);
            #pragma unroll
            for (int r = 0; r < 4; ++r)
                C[(size_t)(rbase + r) * NP + col] = acc[fi][fj][r];
        }
    }
}

// ---------------- per-batch attention (f32 VALU) + split-K reduce ----------------
template<int KS>
__global__ __launch_bounds__(256) void attn_kernel(
    const float* __restrict__ part,
    const float* __restrict__ x,
    const float* __restrict__ imap,
    float* __restrict__ dout)
{
    const int b = blockIdx.x;
    const int t = threadIdx.x;
    const int l = t & 63;
    const int wv = t >> 6;

    __shared__ float sq[64 * 68];
    __shared__ float sk[64 * 68];   // reused as P with stride 65
    __shared__ float sv[64 * 68];

    const float* base0 = part + (size_t)b * NP;
    const float* base1 = part + (size_t)NB * NP + (size_t)b * NP;

    #pragma unroll
    for (int i = 0; i < 4; ++i) {
        int f4 = i * 256 + t;
        int r = f4 >> 4, c = (f4 & 15) * 4;
        float4 q4 = *(const float4*)(base0 + (size_t)f4 * 4);
        float4 k4 = *(const float4*)(base0 + DD + (size_t)f4 * 4);
        float4 v4 = *(const float4*)(base0 + 2 * DD + (size_t)f4 * 4);
        if (KS == 2) {
            float4 a4 = *(const float4*)(base1 + (size_t)f4 * 4);
            float4 b4 = *(const float4*)(base1 + DD + (size_t)f4 * 4);
            float4 c4 = *(const float4*)(base1 + 2 * DD + (size_t)f4 * 4);
            q4.x += a4.x; q4.y += a4.y; q4.z += a4.z; q4.w += a4.w;
            k4.x += b4.x; k4.y += b4.y; k4.z += b4.z; k4.w += b4.w;
            v4.x += c4.x; v4.y += c4.y; v4.z += c4.z; v4.w += c4.w;
        }
        *(float4*)(&sq[r * 68 + c]) = q4;
        *(float4*)(&sk[r * 68 + c]) = k4;
        *(float4*)(&sv[r * 68 + c]) = v4;
    }
    __syncthreads();

    float accs[16];
    #pragma unroll
    for (int i = 0; i < 16; ++i) accs[i] = 0.f;
    #pragma unroll 4
    for (int f4 = 0; f4 < 16; ++f4) {
        float4 kvv = *(const float4*)(&sk[l * 68 + f4 * 4]);
        #pragma unroll
        for (int i = 0; i < 16; ++i) {
            int h = i * 4 + wv;
            float4 qv = *(const float4*)(&sq[h * 68 + f4 * 4]);
            accs[i] = fmaf(qv.x, kvv.x, fmaf(qv.y, kvv.y, fmaf(qv.z, kvv.z, fmaf(qv.w, kvv.w, accs[i]))));
        }
    }
    __syncthreads();
    #pragma unroll
    for (int i = 0; i < 16; ++i) {
        int h = i * 4 + wv;
        float m = imap[(size_t)b * DD + h * 64 + l];
        sk[h * 65 + l] = accs[i] * 0.125f * m;
    }
    __syncthreads();

    {
        int h = t >> 2, j = t & 3;
        float e[16];
        float mx = -3.0e38f;
        #pragma unroll
        for (int q2 = 0; q2 < 16; ++q2) {
            e[q2] = sk[h * 65 + j * 16 + q2];
            mx = fmaxf(mx, e[q2]);
        }
        mx = fmaxf(mx, __shfl_xor(mx, 1));
        mx = fmaxf(mx, __shfl_xor(mx, 2));
        float s = 0.f;
        #pragma unroll
        for (int q2 = 0; q2 < 16; ++q2) { e[q2] = __expf(e[q2] - mx); s += e[q2]; }
        s += __shfl_xor(s, 1);
        s += __shfl_xor(s, 2);
        float invs = 1.0f / s;
        float* aw = dout + (size_t)NB * DD + (size_t)b * DD + h * 64 + j * 16;
        #pragma unroll
        for (int q2 = 0; q2 < 16; q2 += 4) {
            float4 w4 = {e[q2] * invs, e[q2 + 1] * invs, e[q2 + 2] * invs, e[q2 + 3] * invs};
            *(float4*)(aw + q2) = w4;
            sk[h * 65 + j * 16 + q2 + 0] = w4.x;
            sk[h * 65 + j * 16 + q2 + 1] = w4.y;
            sk[h * 65 + j * 16 + q2 + 2] = w4.z;
            sk[h * 65 + j * 16 + q2 + 3] = w4.w;
        }
    }
    __syncthreads();

    float pacc[16];
    #pragma unroll
    for (int i = 0; i < 16; ++i) pacc[i] = 0.f;
    #pragma unroll 4
    for (int g = 0; g < 64; ++g) {
        float p = sk[l * 65 + g];
        const float4* vr = (const float4*)(&sv[g * 68 + wv * 16]);
        float4 v0 = vr[0], v1 = vr[1], v2 = vr[2], v3 = vr[3];
        pacc[0]  = fmaf(p, v0.x, pacc[0]);
        pacc[1]  = fmaf(p, v0.y, pacc[1]);
        pacc[2]  = fmaf(p, v0.z, pacc[2]);
        pacc[3]  = fmaf(p, v0.w, pacc[3]);
        pacc[4]  = fmaf(p, v1.x, pacc[4]);
        pacc[5]  = fmaf(p, v1.y, pacc[5]);
        pacc[6]  = fmaf(p, v1.z, pacc[6]);
        pacc[7]  = fmaf(p, v1.w, pacc[7]);
        pacc[8]  = fmaf(p, v2.x, pacc[8]);
        pacc[9]  = fmaf(p, v2.y, pacc[9]);
        pacc[10] = fmaf(p, v2.z, pacc[10]);
        pacc[11] = fmaf(p, v2.w, pacc[11]);
        pacc[12] = fmaf(p, v3.x, pacc[12]);
        pacc[13] = fmaf(p, v3.y, pacc[13]);
        pacc[14] = fmaf(p, v3.z, pacc[14]);
        pacc[15] = fmaf(p, v3.w, pacc[15]);
    }
    const size_t ob = (size_t)b * DD + (size_t)(wv * 16) * 64 + l;
    #pragma unroll
    for (int ii = 0; ii < 16; ++ii) {
        size_t o = ob + (size_t)ii * 64;
        dout[o] = x[o] * pacc[ii];
    }
}

extern "C" void kernel_launch(void* const* d_in, const int* in_sizes, int n_in,
                              void* d_out, int out_size, void* d_ws, size_t ws_size,
                              hipStream_t stream) {
    const float* x  = (const float*)d_in[0];
    const float* im = (const float*)d_in[1];
    const float* Wq = (const float*)d_in[2];
    const float* Wk = (const float*)d_in[3];
    const float* Wv = (const float*)d_in[4];
    float* out = (float*)d_out;

    unsigned short* xb = (unsigned short*)d_ws;                        // 4 MiB
    float* part = (float*)((char*)d_ws + (size_t)NB * DD * 2);         // KS * 24 MiB

    const size_t need2 = (size_t)NB * DD * 2 + 2ull * NB * NP * 4;
    const int KS = (ws_size >= need2) ? 2 : 1;

    cvt_bf16_kernel<<<dim3((NB * DD / 8 + 255) / 256), dim3(256), 0, stream>>>(x, xb, NB * DD / 8);

    if (KS == 2) {
        gemm_qkv_kernel<2><<<dim3(192 * 8 * 2), dim3(128), 0, stream>>>(xb, Wq, Wk, Wv, part);
        attn_kernel<2><<<dim3(NB), dim3(256), 0, stream>>>(part, x, im, out);
    } else {
        gemm_qkv_kernel<1><<<dim3(192 * 8 * 1), dim3(128), 0, stream>>>(xb, Wq, Wk, Wv, part);
        attn_kernel<1><<<dim3(NB), dim3(256), 0, stream>>>(part, x, im, out);
    }
}

// Round 14
// 142.675 us; speedup vs baseline: 1.8307x; 1.8240x over previous
//
#include <hip/hip_runtime.h>
#include <cstdint>
#include <cstddef>

typedef __attribute__((ext_vector_type(8))) short short8;
typedef __attribute__((ext_vector_type(4))) float f32x4;
typedef __attribute__((ext_vector_type(2))) unsigned int u32x2;

#define NB 512
#define DD 4096
#define NP 12288   // fused N' = 3*DD  (q | k | v)

// hardware packed f32x2 -> bf16x2 (RNE), 1 VALU op
__device__ __forceinline__ unsigned pk2(float a, float b) {
    unsigned r;
    asm("v_cvt_pk_bf16_f32 %0, %1, %2" : "=v"(r) : "v"(a), "v"(b));
    return r;
}
__device__ __forceinline__ unsigned short f2b(float a) {
    return (unsigned short)pk2(a, a);
}
__device__ __forceinline__ float2 ub2(unsigned u) {
    float2 r;
    r.x = __uint_as_float(u << 16);
    r.y = __uint_as_float(u & 0xffff0000u);
    return r;
}

__device__ __forceinline__ void gload_lds16(const void* g, void* l) {
    __builtin_amdgcn_global_load_lds((const __attribute__((address_space(1))) void*)g,
                                     (__attribute__((address_space(3))) void*)l, 16, 0, 0);
}

// ---------------- x -> bf16 ----------------
__global__ __launch_bounds__(256) void cvt_bf16_kernel(const float* __restrict__ src,
                                                       unsigned short* __restrict__ dst,
                                                       int n8) {
    int i = blockIdx.x * 256 + threadIdx.x;
    if (i >= n8) return;
    const float4* s = (const float4*)src + (size_t)i * 2;
    float4 a = s[0], b = s[1];
    uint4 r;
    r.x = pk2(a.x, a.y);
    r.y = pk2(a.z, a.w);
    r.z = pk2(b.x, b.y);
    r.w = pk2(b.z, b.w);
    ((uint4*)dst)[i] = r;
}

// ---------------- fused qkv GEMM (R8 race-free pipeline + bf16 nt partials) ----------------
// 4 waves x (128M x 32N) strips; W loaded straight to registers as fragments.
// Each body issues exactly 6 vmem ops (2 STAGEA + 4 LOADB); end-of-body
// s_waitcnt vmcnt(6) drains everything issued >= 1 body ago, independent of
// intra-body issue order. Consumers 2 bodies downstream: As 4-buffer (stage
// kt+2), W banks 2 (load kt+2). Partials stored bf16 NON-TEMPORAL (no L3
// allocation) so the 201 MB W stream stays L3-resident across replays.
template<int KS>
__global__ __launch_bounds__(256, 3) void gemm_qkv_kernel(
    const unsigned short* __restrict__ xb,
    const float* __restrict__ w0, const float* __restrict__ w1, const float* __restrict__ w2,
    unsigned short* __restrict__ part)
{
    constexpr int KLEN = DD / KS;
    constexpr int NIT = KLEN / 32;
    constexpr int NWG = 96 * 4 * KS;
    constexpr int CPX = NWG / 8;

    // XCD-aware bijective swizzle: blocks sharing a W panel land on one XCD.
    const int bid = blockIdx.x;
    const int orig = (bid & 7) * CPX + (bid >> 3);
    const int nt = orig / (4 * KS);
    const int rest = orig - nt * (4 * KS);
    const int mt = rest / KS;
    const int kz = rest - mt * KS;

    const float* W = (nt < 32) ? w0 : ((nt < 64) ? w1 : w2);
    const int ntl = nt & 31;
    const unsigned short* Abase = xb + (size_t)(mt * 128) * DD + kz * KLEN;
    unsigned short* C = part + (size_t)kz * NB * NP;

    __shared__ unsigned short As[4][128 * 32];   // 32 KB

    const int t = threadIdx.x;
    const int l = t & 63;
    const int wv = t >> 6;          // wave = 32-col strip of W

    f32x4 acc[8][2];
    #pragma unroll
    for (int i = 0; i < 8; ++i)
        #pragma unroll
        for (int j = 0; j < 2; ++j)
            acc[i][j] = (f32x4){0.f, 0.f, 0.f, 0.f};

    // A staging (global_load_lds, linear dest; source chunk pre-swizzled: c ^= (row>>1)&3)
    const int arow0 = (t >> 2);
    const int acol  = (((t & 3) ^ ((t >> 3) & 3)) * 8);
    // A fragment read chunk xor (lane-const)
    const int cx = ((l >> 4) ^ ((l >> 1) & 3));

    // W direct-from-global fragment source: lane l covers W row (strip + fj*16 + (l&15)),
    // k = kt*32 + (l>>4)*8 .. +8 (two float4 halves).
    const float* wsrc = W + (size_t)(ntl * 128 + wv * 32 + (l & 15)) * DD + kz * KLEN + (l >> 4) * 8;

    float4 bank0[2][2], bank1[2][2];   // [fj][half]

    #define LOADB(bk, kt) { _Pragma("unroll") for (int fj = 0; fj < 2; ++fj) \
                              _Pragma("unroll") for (int h = 0; h < 2; ++h) \
                                bk[fj][h] = *(const float4*)(wsrc + (size_t)(fj * 16) * DD + (kt) * 32 + h * 4); }
    #define STAGEA(kt, buf) { _Pragma("unroll") for (int i = 0; i < 2; ++i) \
                               gload_lds16(Abase + (size_t)(i * 64 + arow0) * DD + (kt) * 32 + acol, \
                                           (char*)(&As[buf][0]) + i * 4096 + wv * 1024); }

    #define BODY(kt, BK, PF_OK, VMC) { \
        short8 bfr[2]; \
        _Pragma("unroll") for (int fj = 0; fj < 2; ++fj) { \
            union { uint4 u; short8 s; } cv; \
            cv.u.x = pk2(BK[fj][0].x, BK[fj][0].y); \
            cv.u.y = pk2(BK[fj][0].z, BK[fj][0].w); \
            cv.u.z = pk2(BK[fj][1].x, BK[fj][1].y); \
            cv.u.w = pk2(BK[fj][1].z, BK[fj][1].w); \
            bfr[fj] = cv.s; \
        } \
        if (PF_OK) { STAGEA((kt) + 2, ((kt) + 2) & 3); LOADB(BK, (kt) + 2); } \
        __builtin_amdgcn_s_setprio(1); \
        _Pragma("unroll") for (int fi = 0; fi < 8; ++fi) { \
            int row = fi * 16 + (l & 15); \
            short8 af = *(const short8*)((const char*)(&As[(kt) & 3][0]) + row * 64 + cx * 16); \
            acc[fi][0] = __builtin_amdgcn_mfma_f32_16x16x32_bf16(af, bfr[0], acc[fi][0], 0, 0, 0); \
            acc[fi][1] = __builtin_amdgcn_mfma_f32_16x16x32_bf16(af, bfr[1], acc[fi][1], 0, 0, 0); \
        } \
        __builtin_amdgcn_s_setprio(0); \
        asm volatile("s_waitcnt vmcnt(" #VMC ") lgkmcnt(0)" ::: "memory"); \
        __builtin_amdgcn_sched_barrier(0); \
        __builtin_amdgcn_s_barrier(); \
        __builtin_amdgcn_sched_barrier(0); \
    }

    // prologue: A0,A1 staged; W0,W1 -> banks; full drain.
    STAGEA(0, 0);
    STAGEA(1, 1);
    LOADB(bank0, 0);
    LOADB(bank1, 1);
    asm volatile("s_waitcnt vmcnt(0) lgkmcnt(0)" ::: "memory");
    __builtin_amdgcn_s_barrier();
    __builtin_amdgcn_sched_barrier(0);

    // main: each body leaves its own 6 vmem ops in flight (vmcnt(6)),
    // draining the previous body's 6 regardless of intra-body issue order.
    for (int kt = 0; kt + 2 < NIT; kt += 2) {
        BODY(kt,     bank0, true, 6);
        BODY(kt + 1, bank1, true, 6);
    }
    // tail (NIT even): full drains, no prefetch.
    BODY(NIT - 2, bank0, false, 0);
    BODY(NIT - 1, bank1, false, 0);

    #undef BODY
    #undef LOADB
    #undef STAGEA

    // epilogue: bf16 non-temporal stores (no L3 allocation)
    #pragma unroll
    for (int fi = 0; fi < 8; ++fi) {
        int rbase = mt * 128 + fi * 16 + (l >> 4) * 4;
        #pragma unroll
        for (int fj = 0; fj < 2; ++fj) {
            int col = nt * 128 + wv * 32 + fj * 16 + (l & 15);
            #pragma unroll
            for (int r = 0; r < 4; ++r) {
                unsigned short h = f2b(acc[fi][fj][r]);
                __builtin_nontemporal_store(h, &C[(size_t)(rbase + r) * NP + col]);
            }
        }
    }
}

// ---------------- per-batch attention (f32 VALU) + split-K reduce ----------------
// part is bf16, read with non-temporal loads (stream once, don't pollute L3).
template<int KS>
__global__ __launch_bounds__(256) void attn_kernel(
    const unsigned short* __restrict__ part,
    const float* __restrict__ x,
    const float* __restrict__ imap,
    float* __restrict__ dout)
{
    const int b = blockIdx.x;
    const int t = threadIdx.x;
    const int l = t & 63;
    const int wv = t >> 6;

    __shared__ float sq[64 * 68];
    __shared__ float sk[64 * 68];   // reused as P with stride 65
    __shared__ float sv[64 * 68];

    const unsigned short* base0 = part + (size_t)b * NP;
    const unsigned short* base1 = part + (size_t)NB * NP + (size_t)b * NP;

    #pragma unroll
    for (int i = 0; i < 4; ++i) {
        int f4 = i * 256 + t;                 // 4-elem group index within 1024
        int r = f4 >> 4, c = (f4 & 15) * 4;
        u32x2 qa = __builtin_nontemporal_load((const u32x2*)(base0 + (size_t)f4 * 4));
        u32x2 ka = __builtin_nontemporal_load((const u32x2*)(base0 + DD + (size_t)f4 * 4));
        u32x2 va = __builtin_nontemporal_load((const u32x2*)(base0 + 2 * DD + (size_t)f4 * 4));
        float2 q0 = ub2(qa.x), q1 = ub2(qa.y);
        float2 k0 = ub2(ka.x), k1 = ub2(ka.y);
        float2 v0 = ub2(va.x), v1 = ub2(va.y);
        float4 q4 = {q0.x, q0.y, q1.x, q1.y};
        float4 k4 = {k0.x, k0.y, k1.x, k1.y};
        float4 v4 = {v0.x, v0.y, v1.x, v1.y};
        if (KS == 2) {
            u32x2 qb = __builtin_nontemporal_load((const u32x2*)(base1 + (size_t)f4 * 4));
            u32x2 kb = __builtin_nontemporal_load((const u32x2*)(base1 + DD + (size_t)f4 * 4));
            u32x2 vb = __builtin_nontemporal_load((const u32x2*)(base1 + 2 * DD + (size_t)f4 * 4));
            float2 a0 = ub2(qb.x), a1 = ub2(qb.y);
            float2 b0 = ub2(kb.x), b1 = ub2(kb.y);
            float2 c0 = ub2(vb.x), c1 = ub2(vb.y);
            q4.x += a0.x; q4.y += a0.y; q4.z += a1.x; q4.w += a1.y;
            k4.x += b0.x; k4.y += b0.y; k4.z += b1.x; k4.w += b1.y;
            v4.x += c0.x; v4.y += c0.y; v4.z += c1.x; v4.w += c1.y;
        }
        *(float4*)(&sq[r * 68 + c]) = q4;
        *(float4*)(&sk[r * 68 + c]) = k4;
        *(float4*)(&sv[r * 68 + c]) = v4;
    }
    __syncthreads();

    float accs[16];
    #pragma unroll
    for (int i = 0; i < 16; ++i) accs[i] = 0.f;
    #pragma unroll 4
    for (int f4 = 0; f4 < 16; ++f4) {
        float4 kvv = *(const float4*)(&sk[l * 68 + f4 * 4]);
        #pragma unroll
        for (int i = 0; i < 16; ++i) {
            int h = i * 4 + wv;
            float4 qv = *(const float4*)(&sq[h * 68 + f4 * 4]);
            accs[i] = fmaf(qv.x, kvv.x, fmaf(qv.y, kvv.y, fmaf(qv.z, kvv.z, fmaf(qv.w, kvv.w, accs[i]))));
        }
    }
    __syncthreads();
    #pragma unroll
    for (int i = 0; i < 16; ++i) {
        int h = i * 4 + wv;
        float m = imap[(size_t)b * DD + h * 64 + l];
        sk[h * 65 + l] = accs[i] * 0.125f * m;
    }
    __syncthreads();

    {
        int h = t >> 2, j = t & 3;
        float e[16];
        float mx = -3.0e38f;
        #pragma unroll
        for (int q2 = 0; q2 < 16; ++q2) {
            e[q2] = sk[h * 65 + j * 16 + q2];
            mx = fmaxf(mx, e[q2]);
        }
        mx = fmaxf(mx, __shfl_xor(mx, 1));
        mx = fmaxf(mx, __shfl_xor(mx, 2));
        float s = 0.f;
        #pragma unroll
        for (int q2 = 0; q2 < 16; ++q2) { e[q2] = __expf(e[q2] - mx); s += e[q2]; }
        s += __shfl_xor(s, 1);
        s += __shfl_xor(s, 2);
        float invs = 1.0f / s;
        float* aw = dout + (size_t)NB * DD + (size_t)b * DD + h * 64 + j * 16;
        #pragma unroll
        for (int q2 = 0; q2 < 16; q2 += 4) {
            f32x4 w4 = {e[q2] * invs, e[q2 + 1] * invs, e[q2 + 2] * invs, e[q2 + 3] * invs};
            __builtin_nontemporal_store(w4, (f32x4*)(aw + q2));
            sk[h * 65 + j * 16 + q2 + 0] = w4.x;
            sk[h * 65 + j * 16 + q2 + 1] = w4.y;
            sk[h * 65 + j * 16 + q2 + 2] = w4.z;
            sk[h * 65 + j * 16 + q2 + 3] = w4.w;
        }
    }
    __syncthreads();

    float pacc[16];
    #pragma unroll
    for (int i = 0; i < 16; ++i) pacc[i] = 0.f;
    #pragma unroll 4
    for (int g = 0; g < 64; ++g) {
        float p = sk[l * 65 + g];
        const float4* vr = (const float4*)(&sv[g * 68 + wv * 16]);
        float4 v0 = vr[0], v1 = vr[1], v2 = vr[2], v3 = vr[3];
        pacc[0]  = fmaf(p, v0.x, pacc[0]);
        pacc[1]  = fmaf(p, v0.y, pacc[1]);
        pacc[2]  = fmaf(p, v0.z, pacc[2]);
        pacc[3]  = fmaf(p, v0.w, pacc[3]);
        pacc[4]  = fmaf(p, v1.x, pacc[4]);
        pacc[5]  = fmaf(p, v1.y, pacc[5]);
        pacc[6]  = fmaf(p, v1.z, pacc[6]);
        pacc[7]  = fmaf(p, v1.w, pacc[7]);
        pacc[8]  = fmaf(p, v2.x, pacc[8]);
        pacc[9]  = fmaf(p, v2.y, pacc[9]);
        pacc[10] = fmaf(p, v2.z, pacc[10]);
        pacc[11] = fmaf(p, v2.w, pacc[11]);
        pacc[12] = fmaf(p, v3.x, pacc[12]);
        pacc[13] = fmaf(p, v3.y, pacc[13]);
        pacc[14] = fmaf(p, v3.z, pacc[14]);
        pacc[15] = fmaf(p, v3.w, pacc[15]);
    }
    const size_t ob = (size_t)b * DD + (size_t)(wv * 16) * 64 + l;
    #pragma unroll
    for (int ii = 0; ii < 16; ++ii) {
        size_t o = ob + (size_t)ii * 64;
        float r = x[o] * pacc[ii];
        __builtin_nontemporal_store(r, &dout[o]);
    }
}

extern "C" void kernel_launch(void* const* d_in, const int* in_sizes, int n_in,
                              void* d_out, int out_size, void* d_ws, size_t ws_size,
                              hipStream_t stream) {
    const float* x  = (const float*)d_in[0];
    const float* im = (const float*)d_in[1];
    const float* Wq = (const float*)d_in[2];
    const float* Wk = (const float*)d_in[3];
    const float* Wv = (const float*)d_in[4];
    float* out = (float*)d_out;

    unsigned short* xb = (unsigned short*)d_ws;                             // 4 MiB
    unsigned short* part = (unsigned short*)((char*)d_ws + (size_t)NB * DD * 2);  // KS * 12 MiB (bf16)

    const size_t need2 = (size_t)NB * DD * 2 + 2ull * NB * NP * 2;
    const int KS = (ws_size >= need2) ? 2 : 1;

    cvt_bf16_kernel<<<dim3((NB * DD / 8 + 255) / 256), dim3(256), 0, stream>>>(x, xb, NB * DD / 8);

    if (KS == 2) {
        gemm_qkv_kernel<2><<<dim3(96 * 4 * 2), dim3(256), 0, stream>>>(xb, Wq, Wk, Wv, part);
        attn_kernel<2><<<dim3(NB), dim3(256), 0, stream>>>(part, x, im, out);
    } else {
        gemm_qkv_kernel<1><<<dim3(96 * 4 * 1), dim3(256), 0, stream>>>(xb, Wq, Wk, Wv, part);
        attn_kernel<1><<<dim3(NB), dim3(256), 0, stream>>>(part, x, im, out);
    }
}

// Round 15
// 141.602 us; speedup vs baseline: 1.8446x; 1.0076x over previous
//
#include <hip/hip_runtime.h>
#include <cstdint>
#include <cstddef>

typedef __attribute__((ext_vector_type(8))) short short8;
typedef __attribute__((ext_vector_type(4))) float f32x4;
typedef __attribute__((ext_vector_type(2))) unsigned int u32x2;

#define NB 512
#define DD 4096
#define NP 12288   // fused N' = 3*DD  (q | k | v)

// s_waitcnt with vmcnt=vm, lgkmcnt=0, expcnt=don't-care (gfx9 encoding)
#define SWAIT(vm) __builtin_amdgcn_s_waitcnt(((vm) & 15) | (7 << 4) | ((((vm) >> 4) & 3) << 14))

// hardware packed f32x2 -> bf16x2 (RNE), 1 VALU op
__device__ __forceinline__ unsigned pk2(float a, float b) {
    unsigned r;
    asm("v_cvt_pk_bf16_f32 %0, %1, %2" : "=v"(r) : "v"(a), "v"(b));
    return r;
}
__device__ __forceinline__ unsigned short f2b(float a) {
    return (unsigned short)pk2(a, a);
}
__device__ __forceinline__ float2 ub2(unsigned u) {
    float2 r;
    r.x = __uint_as_float(u << 16);
    r.y = __uint_as_float(u & 0xffff0000u);
    return r;
}

__device__ __forceinline__ void gload_lds16(const void* g, void* l) {
    __builtin_amdgcn_global_load_lds((const __attribute__((address_space(1))) void*)g,
                                     (__attribute__((address_space(3))) void*)l, 16, 0, 0);
}

// ---------------- x -> bf16 ----------------
__global__ __launch_bounds__(256) void cvt_bf16_kernel(const float* __restrict__ src,
                                                       unsigned short* __restrict__ dst,
                                                       int n8) {
    int i = blockIdx.x * 256 + threadIdx.x;
    if (i >= n8) return;
    const float4* s = (const float4*)src + (size_t)i * 2;
    float4 a = s[0], b = s[1];
    uint4 r;
    r.x = pk2(a.x, a.y);
    r.y = pk2(a.z, a.w);
    r.z = pk2(b.x, b.y);
    r.w = pk2(b.z, b.w);
    ((uint4*)dst)[i] = r;
}

// ---------------- fused qkv GEMM: R14 structure, prefetch depth 3 ----------------
// 4 waves x (128M x 32N); W direct global->reg, 3 banks; A via global_load_lds,
// 5 LDS buffers. Body kt issues A[kt+3] + W[kt+3] (6 vmem ops); end-of-body
// s_waitcnt vmcnt(12) leaves the last TWO bodies' ops in flight and drains
// everything older — order-independent. Consumers are 3 bodies downstream.
template<int KS>
__global__ __launch_bounds__(256, 3) void gemm_qkv_kernel(
    const unsigned short* __restrict__ xb,
    const float* __restrict__ w0, const float* __restrict__ w1, const float* __restrict__ w2,
    unsigned short* __restrict__ part)
{
    constexpr int KLEN = DD / KS;
    constexpr int NIT = KLEN / 32;
    constexpr int KMAIN = ((NIT - 3) / 15) * 15;   // 60 (KS=2) / 120 (KS=1)
    constexpr int NWG = 96 * 4 * KS;
    constexpr int CPX = NWG / 8;

    // XCD-aware bijective swizzle: blocks sharing a W panel land on one XCD.
    const int bid = blockIdx.x;
    const int orig = (bid & 7) * CPX + (bid >> 3);
    const int nt = orig / (4 * KS);
    const int rest = orig - nt * (4 * KS);
    const int mt = rest / KS;
    const int kz = rest - mt * KS;

    const float* W = (nt < 32) ? w0 : ((nt < 64) ? w1 : w2);
    const int ntl = nt & 31;
    const unsigned short* Abase = xb + (size_t)(mt * 128) * DD + kz * KLEN;
    unsigned short* C = part + (size_t)kz * NB * NP;

    __shared__ unsigned short As[5][128 * 32];   // 40 KB

    const int t = threadIdx.x;
    const int l = t & 63;
    const int wv = t >> 6;          // wave = 32-col strip of W

    f32x4 acc[8][2];
    #pragma unroll
    for (int i = 0; i < 8; ++i)
        #pragma unroll
        for (int j = 0; j < 2; ++j)
            acc[i][j] = (f32x4){0.f, 0.f, 0.f, 0.f};

    // A staging (global_load_lds, linear dest; source chunk pre-swizzled: c ^= (row>>1)&3)
    const int arow0 = (t >> 2);
    const int acol  = (((t & 3) ^ ((t >> 3) & 3)) * 8);
    // A fragment read chunk xor (lane-const)
    const int cx = ((l >> 4) ^ ((l >> 1) & 3));

    // W direct-from-global fragment source: lane l covers W row (strip + fj*16 + (l&15)),
    // k = kt*32 + (l>>4)*8 .. +8 (two float4 halves).
    const float* wsrc = W + (size_t)(ntl * 128 + wv * 32 + (l & 15)) * DD + kz * KLEN + (l >> 4) * 8;

    float4 b0[2][2], b1[2][2], b2[2][2];   // 3 W banks [fj][half]

    #define LOADB(bk, kt) { _Pragma("unroll") for (int fj = 0; fj < 2; ++fj) \
                              _Pragma("unroll") for (int h = 0; h < 2; ++h) \
                                bk[fj][h] = *(const float4*)(wsrc + (size_t)(fj * 16) * DD + (kt) * 32 + h * 4); }
    #define STAGEA(kt, buf) { _Pragma("unroll") for (int i = 0; i < 2; ++i) \
                               gload_lds16(Abase + (size_t)(i * 64 + arow0) * DD + (kt) * 32 + acol, \
                                           (char*)(&As[buf][0]) + i * 4096 + wv * 1024); }

    #define CORE(BUF, BK) { \
        short8 bfr[2]; \
        _Pragma("unroll") for (int fj = 0; fj < 2; ++fj) { \
            union { uint4 u; short8 s; } cv; \
            cv.u.x = pk2(BK[fj][0].x, BK[fj][0].y); \
            cv.u.y = pk2(BK[fj][0].z, BK[fj][0].w); \
            cv.u.z = pk2(BK[fj][1].x, BK[fj][1].y); \
            cv.u.w = pk2(BK[fj][1].z, BK[fj][1].w); \
            bfr[fj] = cv.s; \
        } \
        __builtin_amdgcn_s_setprio(1); \
        _Pragma("unroll") for (int fi = 0; fi < 8; ++fi) { \
            int row = fi * 16 + (l & 15); \
            short8 af = *(const short8*)((const char*)(&As[BUF][0]) + row * 64 + cx * 16); \
            acc[fi][0] = __builtin_amdgcn_mfma_f32_16x16x32_bf16(af, bfr[0], acc[fi][0], 0, 0, 0); \
            acc[fi][1] = __builtin_amdgcn_mfma_f32_16x16x32_bf16(af, bfr[1], acc[fi][1], 0, 0, 0); \
        } \
        __builtin_amdgcn_s_setprio(0); \
    }

    #define ENDBAR(VMC) { \
        SWAIT(VMC); \
        __builtin_amdgcn_sched_barrier(0); \
        __builtin_amdgcn_s_barrier(); \
        __builtin_amdgcn_sched_barrier(0); }

    // main body: consume (I%5, bank), prefetch kt+3 -> buffer (I+3)%5 + same bank.
    // NOTE: cvt (in CORE) reads the bank BEFORE LOADB rewrites it, but LOADB must
    // be issued before the long MFMA block -> split: cvt first, then PF, then MFMA.
    #define ITER_M(kt, I, BK) { \
        short8 bfr[2]; \
        _Pragma("unroll") for (int fj = 0; fj < 2; ++fj) { \
            union { uint4 u; short8 s; } cv; \
            cv.u.x = pk2(BK[fj][0].x, BK[fj][0].y); \
            cv.u.y = pk2(BK[fj][0].z, BK[fj][0].w); \
            cv.u.z = pk2(BK[fj][1].x, BK[fj][1].y); \
            cv.u.w = pk2(BK[fj][1].z, BK[fj][1].w); \
            bfr[fj] = cv.s; \
        } \
        STAGEA((kt) + 3, ((I) + 3) % 5); \
        LOADB(BK, (kt) + 3); \
        __builtin_amdgcn_s_setprio(1); \
        _Pragma("unroll") for (int fi = 0; fi < 8; ++fi) { \
            int row = fi * 16 + (l & 15); \
            short8 af = *(const short8*)((const char*)(&As[(I) % 5][0]) + row * 64 + cx * 16); \
            acc[fi][0] = __builtin_amdgcn_mfma_f32_16x16x32_bf16(af, bfr[0], acc[fi][0], 0, 0, 0); \
            acc[fi][1] = __builtin_amdgcn_mfma_f32_16x16x32_bf16(af, bfr[1], acc[fi][1], 0, 0, 0); \
        } \
        __builtin_amdgcn_s_setprio(0); \
        ENDBAR(12); \
    }

    // tail body: constexpr prefetch + vmcnt wind-down
    #define ITER_T(J, BK) { \
        constexpr int kt_ = KMAIN + (J); \
        if (kt_ < NIT) { \
            constexpr bool PF_ = (kt_ + 3 < NIT); \
            constexpr int VMC_ = 6 * ((kt_ + 2 < NIT) ? 1 : 0) + 6 * ((kt_ + 3 < NIT) ? 1 : 0); \
            short8 bfr[2]; \
            _Pragma("unroll") for (int fj = 0; fj < 2; ++fj) { \
                union { uint4 u; short8 s; } cv; \
                cv.u.x = pk2(BK[fj][0].x, BK[fj][0].y); \
                cv.u.y = pk2(BK[fj][0].z, BK[fj][0].w); \
                cv.u.z = pk2(BK[fj][1].x, BK[fj][1].y); \
                cv.u.w = pk2(BK[fj][1].z, BK[fj][1].w); \
                bfr[fj] = cv.s; \
            } \
            if (PF_) { STAGEA(kt_ + 3, ((J) + 3) % 5); LOADB(BK, kt_ + 3); } \
            __builtin_amdgcn_s_setprio(1); \
            _Pragma("unroll") for (int fi = 0; fi < 8; ++fi) { \
                int row = fi * 16 + (l & 15); \
                short8 af = *(const short8*)((const char*)(&As[(J) % 5][0]) + row * 64 + cx * 16); \
                acc[fi][0] = __builtin_amdgcn_mfma_f32_16x16x32_bf16(af, bfr[0], acc[fi][0], 0, 0, 0); \
                acc[fi][1] = __builtin_amdgcn_mfma_f32_16x16x32_bf16(af, bfr[1], acc[fi][1], 0, 0, 0); \
            } \
            __builtin_amdgcn_s_setprio(0); \
            ENDBAR(VMC_); \
        } }

    // prologue: A0..A2 staged into bufs 0..2; W0..W2 -> banks; full drain.
    STAGEA(0, 0);
    STAGEA(1, 1);
    STAGEA(2, 2);
    LOADB(b0, 0);
    LOADB(b1, 1);
    LOADB(b2, 2);
    SWAIT(0);
    __builtin_amdgcn_s_barrier();
    __builtin_amdgcn_sched_barrier(0);

    for (int kt0 = 0; kt0 < KMAIN; kt0 += 15) {
        ITER_M(kt0 + 0,  0,  b0);
        ITER_M(kt0 + 1,  1,  b1);
        ITER_M(kt0 + 2,  2,  b2);
        ITER_M(kt0 + 3,  3,  b0);
        ITER_M(kt0 + 4,  4,  b1);
        ITER_M(kt0 + 5,  5,  b2);
        ITER_M(kt0 + 6,  6,  b0);
        ITER_M(kt0 + 7,  7,  b1);
        ITER_M(kt0 + 8,  8,  b2);
        ITER_M(kt0 + 9,  9,  b0);
        ITER_M(kt0 + 10, 10, b1);
        ITER_M(kt0 + 11, 11, b2);
        ITER_M(kt0 + 12, 12, b0);
        ITER_M(kt0 + 13, 13, b1);
        ITER_M(kt0 + 14, 14, b2);
    }
    // tails (4 for KS=2, 8 for KS=1); KMAIN % 15 == 0 so bank/buf patterns continue
    ITER_T(0, b0);
    ITER_T(1, b1);
    ITER_T(2, b2);
    ITER_T(3, b0);
    ITER_T(4, b1);
    ITER_T(5, b2);
    ITER_T(6, b0);
    ITER_T(7, b1);

    #undef ITER_M
    #undef ITER_T
    #undef CORE
    #undef ENDBAR
    #undef LOADB
    #undef STAGEA

    // epilogue: bf16 non-temporal stores (no L3 allocation)
    #pragma unroll
    for (int fi = 0; fi < 8; ++fi) {
        int rbase = mt * 128 + fi * 16 + (l >> 4) * 4;
        #pragma unroll
        for (int fj = 0; fj < 2; ++fj) {
            int col = nt * 128 + wv * 32 + fj * 16 + (l & 15);
            #pragma unroll
            for (int r = 0; r < 4; ++r) {
                unsigned short h = f2b(acc[fi][fj][r]);
                __builtin_nontemporal_store(h, &C[(size_t)(rbase + r) * NP + col]);
            }
        }
    }
}

// ---------------- per-batch attention (f32 VALU) + split-K reduce ----------------
template<int KS>
__global__ __launch_bounds__(256) void attn_kernel(
    const unsigned short* __restrict__ part,
    const float* __restrict__ x,
    const float* __restrict__ imap,
    float* __restrict__ dout)
{
    const int b = blockIdx.x;
    const int t = threadIdx.x;
    const int l = t & 63;
    const int wv = t >> 6;

    __shared__ float sq[64 * 68];
    __shared__ float sk[64 * 68];   // reused as P with stride 65
    __shared__ float sv[64 * 68];

    const unsigned short* base0 = part + (size_t)b * NP;
    const unsigned short* base1 = part + (size_t)NB * NP + (size_t)b * NP;

    #pragma unroll
    for (int i = 0; i < 4; ++i) {
        int f4 = i * 256 + t;
        int r = f4 >> 4, c = (f4 & 15) * 4;
        u32x2 qa = __builtin_nontemporal_load((const u32x2*)(base0 + (size_t)f4 * 4));
        u32x2 ka = __builtin_nontemporal_load((const u32x2*)(base0 + DD + (size_t)f4 * 4));
        u32x2 va = __builtin_nontemporal_load((const u32x2*)(base0 + 2 * DD + (size_t)f4 * 4));
        float2 q0 = ub2(qa.x), q1 = ub2(qa.y);
        float2 k0 = ub2(ka.x), k1 = ub2(ka.y);
        float2 v0 = ub2(va.x), v1 = ub2(va.y);
        float4 q4 = {q0.x, q0.y, q1.x, q1.y};
        float4 k4 = {k0.x, k0.y, k1.x, k1.y};
        float4 v4 = {v0.x, v0.y, v1.x, v1.y};
        if (KS == 2) {
            u32x2 qb = __builtin_nontemporal_load((const u32x2*)(base1 + (size_t)f4 * 4));
            u32x2 kb = __builtin_nontemporal_load((const u32x2*)(base1 + DD + (size_t)f4 * 4));
            u32x2 vb = __builtin_nontemporal_load((const u32x2*)(base1 + 2 * DD + (size_t)f4 * 4));
            float2 a0 = ub2(qb.x), a1 = ub2(qb.y);
            float2 b0 = ub2(kb.x), b1 = ub2(kb.y);
            float2 c0 = ub2(vb.x), c1 = ub2(vb.y);
            q4.x += a0.x; q4.y += a0.y; q4.z += a1.x; q4.w += a1.y;
            k4.x += b0.x; k4.y += b0.y; k4.z += b1.x; k4.w += b1.y;
            v4.x += c0.x; v4.y += c0.y; v4.z += c1.x; v4.w += c1.y;
        }
        *(float4*)(&sq[r * 68 + c]) = q4;
        *(float4*)(&sk[r * 68 + c]) = k4;
        *(float4*)(&sv[r * 68 + c]) = v4;
    }
    __syncthreads();

    float accs[16];
    #pragma unroll
    for (int i = 0; i < 16; ++i) accs[i] = 0.f;
    #pragma unroll 4
    for (int f4 = 0; f4 < 16; ++f4) {
        float4 kvv = *(const float4*)(&sk[l * 68 + f4 * 4]);
        #pragma unroll
        for (int i = 0; i < 16; ++i) {
            int h = i * 4 + wv;
            float4 qv = *(const float4*)(&sq[h * 68 + f4 * 4]);
            accs[i] = fmaf(qv.x, kvv.x, fmaf(qv.y, kvv.y, fmaf(qv.z, kvv.z, fmaf(qv.w, kvv.w, accs[i]))));
        }
    }
    __syncthreads();
    #pragma unroll
    for (int i = 0; i < 16; ++i) {
        int h = i * 4 + wv;
        float m = imap[(size_t)b * DD + h * 64 + l];
        sk[h * 65 + l] = accs[i] * 0.125f * m;
    }
    __syncthreads();

    {
        int h = t >> 2, j = t & 3;
        float e[16];
        float mx = -3.0e38f;
        #pragma unroll
        for (int q2 = 0; q2 < 16; ++q2) {
            e[q2] = sk[h * 65 + j * 16 + q2];
            mx = fmaxf(mx, e[q2]);
        }
        mx = fmaxf(mx, __shfl_xor(mx, 1));
        mx = fmaxf(mx, __shfl_xor(mx, 2));
        float s = 0.f;
        #pragma unroll
        for (int q2 = 0; q2 < 16; ++q2) { e[q2] = __expf(e[q2] - mx); s += e[q2]; }
        s += __shfl_xor(s, 1);
        s += __shfl_xor(s, 2);
        float invs = 1.0f / s;
        float* aw = dout + (size_t)NB * DD + (size_t)b * DD + h * 64 + j * 16;
        #pragma unroll
        for (int q2 = 0; q2 < 16; q2 += 4) {
            f32x4 w4 = {e[q2] * invs, e[q2 + 1] * invs, e[q2 + 2] * invs, e[q2 + 3] * invs};
            __builtin_nontemporal_store(w4, (f32x4*)(aw + q2));
            sk[h * 65 + j * 16 + q2 + 0] = w4.x;
            sk[h * 65 + j * 16 + q2 + 1] = w4.y;
            sk[h * 65 + j * 16 + q2 + 2] = w4.z;
            sk[h * 65 + j * 16 + q2 + 3] = w4.w;
        }
    }
    __syncthreads();

    float pacc[16];
    #pragma unroll
    for (int i = 0; i < 16; ++i) pacc[i] = 0.f;
    #pragma unroll 4
    for (int g = 0; g < 64; ++g) {
        float p = sk[l * 65 + g];
        const float4* vr = (const float4*)(&sv[g * 68 + wv * 16]);
        float4 v0 = vr[0], v1 = vr[1], v2 = vr[2], v3 = vr[3];
        pacc[0]  = fmaf(p, v0.x, pacc[0]);
        pacc[1]  = fmaf(p, v0.y, pacc[1]);
        pacc[2]  = fmaf(p, v0.z, pacc[2]);
        pacc[3]  = fmaf(p, v0.w, pacc[3]);
        pacc[4]  = fmaf(p, v1.x, pacc[4]);
        pacc[5]  = fmaf(p, v1.y, pacc[5]);
        pacc[6]  = fmaf(p, v1.z, pacc[6]);
        pacc[7]  = fmaf(p, v1.w, pacc[7]);
        pacc[8]  = fmaf(p, v2.x, pacc[8]);
        pacc[9]  = fmaf(p, v2.y, pacc[9]);
        pacc[10] = fmaf(p, v2.z, pacc[10]);
        pacc[11] = fmaf(p, v2.w, pacc[11]);
        pacc[12] = fmaf(p, v3.x, pacc[12]);
        pacc[13] = fmaf(p, v3.y, pacc[13]);
        pacc[14] = fmaf(p, v3.z, pacc[14]);
        pacc[15] = fmaf(p, v3.w, pacc[15]);
    }
    const size_t ob = (size_t)b * DD + (size_t)(wv * 16) * 64 + l;
    #pragma unroll
    for (int ii = 0; ii < 16; ++ii) {
        size_t o = ob + (size_t)ii * 64;
        float r = x[o] * pacc[ii];
        __builtin_nontemporal_store(r, &dout[o]);
    }
}

extern "C" void kernel_launch(void* const* d_in, const int* in_sizes, int n_in,
                              void* d_out, int out_size, void* d_ws, size_t ws_size,
                              hipStream_t stream) {
    const float* x  = (const float*)d_in[0];
    const float* im = (const float*)d_in[1];
    const float* Wq = (const float*)d_in[2];
    const float* Wk = (const float*)d_in[3];
    const float* Wv = (const float*)d_in[4];
    float* out = (float*)d_out;

    unsigned short* xb = (unsigned short*)d_ws;                             // 4 MiB
    unsigned short* part = (unsigned short*)((char*)d_ws + (size_t)NB * DD * 2);  // KS * 12 MiB (bf16)

    const size_t need2 = (size_t)NB * DD * 2 + 2ull * NB * NP * 2;
    const int KS = (ws_size >= need2) ? 2 : 1;

    cvt_bf16_kernel<<<dim3((NB * DD / 8 + 255) / 256), dim3(256), 0, stream>>>(x, xb, NB * DD / 8);

    if (KS == 2) {
        gemm_qkv_kernel<2><<<dim3(96 * 4 * 2), dim3(256), 0, stream>>>(xb, Wq, Wk, Wv, part);
        attn_kernel<2><<<dim3(NB), dim3(256), 0, stream>>>(part, x, im, out);
    } else {
        gemm_qkv_kernel<1><<<dim3(96 * 4 * 1), dim3(256), 0, stream>>>(xb, Wq, Wk, Wv, part);
        attn_kernel<1><<<dim3(NB), dim3(256), 0, stream>>>(part, x, im, out);
    }
}